// Round 3
// baseline (216.900 us; speedup 1.0000x reference)
//
#include <hip/hip_runtime.h>
#include <math.h>

// NeRF ray integration, v3: persistent grid-stride waves + 2-deep software
// pipeline so global loads stay in flight across the shuffle/exp chain.
// Layout per iteration (same as v2): 2 rays per 64-lane wave (32-lane
// segments), 4 samples per lane, float4 streams.
// wi[s] = exp(-excl_cumsum(sigma*dt)[s]) - exp(-incl_cumsum(sigma*dt)[s])
// dt[s] = t[s+1]-t[s], dt[S-1] = 0 (infinite=False). Output t == input t.

#define NRAYS 65536
#define S 128
#define BLOCKS 2048            // 8 wg/CU on 256 CUs -> full 32 waves/CU
#define RAYS_PER_ITER 8        // per block: 4 waves * 2 rays
#define ITERS (NRAYS / (BLOCKS * RAYS_PER_ITER))   // 4

typedef float __attribute__((ext_vector_type(4))) fvec4;

__global__ __launch_bounds__(256) void nerf_render_kernel(
    const float* __restrict__ t,
    const float* __restrict__ sigma,
    const float* __restrict__ color,
    float* __restrict__ out_color,   // [N,3]
    float* __restrict__ out_depth,   // [N,1]
    float* __restrict__ out_wi,      // [N,S]
    float* __restrict__ out_t)       // [N,S]
{
    const int lane    = threadIdx.x & 63;
    const int seglane = lane & 31;
    const int wave    = threadIdx.x >> 6;
    const int seg     = lane >> 5;                 // which of the 2 rays

    // ray for iteration it: consecutive rays within a block, block-strided
    // across iterations for coalescing: ray = (it*BLOCKS + blockIdx)*8 + ...
    const int sub = wave * 2 + seg;                // 0..7 within block

    // ---- prologue: load iteration 0 ----
    int ray = (0 * BLOCKS + blockIdx.x) * RAYS_PER_ITER + sub;
    long sbase = (long)ray * S + 4 * seglane;
    fvec4 tv = *(const fvec4*)(t + sbase);
    fvec4 sv = *(const fvec4*)(sigma + sbase);
    const fvec4* cp = (const fvec4*)(color + (long)ray * (S * 3) + 12 * seglane);
    fvec4 c0 = cp[0], c1 = cp[1], c2 = cp[2];

    #pragma unroll
    for (int it = 0; it < ITERS; ++it) {
        // ---- prefetch next iteration while current computes ----
        fvec4 ntv, nsv, nc0, nc1, nc2;
        long nsbase = 0;
        if (it + 1 < ITERS) {
            const int nray = ((it + 1) * BLOCKS + blockIdx.x) * RAYS_PER_ITER + sub;
            nsbase = (long)nray * S + 4 * seglane;
            ntv = *(const fvec4*)(t + nsbase);
            nsv = *(const fvec4*)(sigma + nsbase);
            const fvec4* ncp = (const fvec4*)(color + (long)nray * (S * 3) + 12 * seglane);
            nc0 = ncp[0]; nc1 = ncp[1]; nc2 = ncp[2];
        }

        // ---- dt stencil ----
        const float t_next = __shfl_down(tv.x, 1, 32);
        const float dt0 = tv.y - tv.x;
        const float dt1 = tv.z - tv.y;
        const float dt2 = tv.w - tv.z;
        const float dt3 = (seglane == 31) ? 0.0f : (t_next - tv.w);

        const float p0  = sv.x * dt0;
        const float p1  = p0 + sv.y * dt1;
        const float p2  = p1 + sv.z * dt2;
        const float tot = p2 + sv.w * dt3;

        // ---- segment-inclusive scan (5 shfl_up) ----
        float scan = tot;
        #pragma unroll
        for (int off = 1; off < 32; off <<= 1) {
            const float v = __shfl_up(scan, off, 32);
            if (seglane >= off) scan += v;
        }
        const float excl = scan - tot;

        const float E0 = __expf(-excl);
        const float e0 = __expf(-(excl + p0));
        const float e1 = __expf(-(excl + p1));
        const float e2 = __expf(-(excl + p2));
        const float e3 = __expf(-scan);
        const float wi0 = E0 - e0;
        const float wi1 = e0 - e1;
        const float wi2 = e1 - e2;
        const float wi3 = e2 - e3;

        // ---- streamed outputs ----
        fvec4 wiv; wiv.x = wi0; wiv.y = wi1; wiv.z = wi2; wiv.w = wi3;
        __builtin_nontemporal_store(wiv, (fvec4*)(out_wi + sbase));
        __builtin_nontemporal_store(tv,  (fvec4*)(out_t + sbase));

        // ---- per-ray reductions ----
        float r = wi0 * c0.x + wi1 * c0.w + wi2 * c1.z + wi3 * c2.y;
        float g = wi0 * c0.y + wi1 * c1.x + wi2 * c1.w + wi3 * c2.z;
        float b = wi0 * c0.z + wi1 * c1.y + wi2 * c2.x + wi3 * c2.w;
        float d = wi0 * tv.x + wi1 * tv.y + wi2 * tv.z + wi3 * tv.w;

        #pragma unroll
        for (int off = 16; off >= 1; off >>= 1) {
            r += __shfl_xor(r, off, 32);
            g += __shfl_xor(g, off, 32);
            b += __shfl_xor(b, off, 32);
            d += __shfl_xor(d, off, 32);
        }

        if (seglane == 0) {
            out_color[(long)ray * 3 + 0] = r;
            out_color[(long)ray * 3 + 1] = g;
            out_color[(long)ray * 3 + 2] = b;
            out_depth[ray] = d;
        }

        // ---- rotate pipeline ----
        ray = ((it + 1) * BLOCKS + blockIdx.x) * RAYS_PER_ITER + sub;
        sbase = nsbase;
        tv = ntv; sv = nsv; c0 = nc0; c1 = nc1; c2 = nc2;
    }
}

extern "C" void kernel_launch(void* const* d_in, const int* in_sizes, int n_in,
                              void* d_out, int out_size, void* d_ws, size_t ws_size,
                              hipStream_t stream) {
    const float* t     = (const float*)d_in[0];
    const float* sigma = (const float*)d_in[1];
    const float* color = (const float*)d_in[2];

    float* out = (float*)d_out;
    float* out_color = out;                         // N*3
    float* out_depth = out_color + (long)NRAYS * 3; // N
    float* out_wi    = out_depth + NRAYS;           // N*S
    float* out_t     = out_wi + (long)NRAYS * S;    // N*S

    nerf_render_kernel<<<BLOCKS, 256, 0, stream>>>(
        t, sigma, color, out_color, out_depth, out_wi, out_t);
}

// Round 4
// 214.936 us; speedup vs baseline: 1.0091x; 1.0091x over previous
//
#include <hip/hip_runtime.h>
#include <math.h>

// NeRF ray integration, v4: DIAGNOSTIC SPLIT.
// K2: pure float4 copy t -> out_t (known-good 6.3 TB/s pattern on gfx950).
// K1: v2 structure (2 rays/wave, 4 samples/lane, float4) minus the t store.
// If K2's hbm_gbps is also ~2 TB/s, the ~77us pin is environmental
// (L3 writeback drain from harness restore), i.e. roofline.

#define NRAYS 65536
#define S 128
#define RAYS_PER_BLOCK 8   // K1: 4 waves * 2 rays

typedef float __attribute__((ext_vector_type(4))) fvec4;

// ---------------- K1: integrate (no t copy) ----------------
__global__ __launch_bounds__(256) void nerf_integrate_kernel(
    const float* __restrict__ t,
    const float* __restrict__ sigma,
    const float* __restrict__ color,
    float* __restrict__ out_color,   // [N,3]
    float* __restrict__ out_depth,   // [N,1]
    float* __restrict__ out_wi)      // [N,S]
{
    const int lane    = threadIdx.x & 63;
    const int seglane = lane & 31;
    const int wave    = threadIdx.x >> 6;
    const int ray = blockIdx.x * RAYS_PER_BLOCK + wave * 2 + (lane >> 5);

    const long sbase = (long)ray * S + 4 * seglane;

    const fvec4 tv = *(const fvec4*)(t + sbase);
    const fvec4 sv = *(const fvec4*)(sigma + sbase);
    const fvec4* cp = (const fvec4*)(color + (long)ray * (S * 3) + 12 * seglane);
    const fvec4 c0 = cp[0];
    const fvec4 c1 = cp[1];
    const fvec4 c2 = cp[2];

    const float t_next = __shfl_down(tv.x, 1, 32);
    const float dt0 = tv.y - tv.x;
    const float dt1 = tv.z - tv.y;
    const float dt2 = tv.w - tv.z;
    const float dt3 = (seglane == 31) ? 0.0f : (t_next - tv.w);

    const float p0  = sv.x * dt0;
    const float p1  = p0 + sv.y * dt1;
    const float p2  = p1 + sv.z * dt2;
    const float tot = p2 + sv.w * dt3;

    float scan = tot;
    #pragma unroll
    for (int off = 1; off < 32; off <<= 1) {
        const float v = __shfl_up(scan, off, 32);
        if (seglane >= off) scan += v;
    }
    const float excl = scan - tot;

    const float E0 = __expf(-excl);
    const float e0 = __expf(-(excl + p0));
    const float e1 = __expf(-(excl + p1));
    const float e2 = __expf(-(excl + p2));
    const float e3 = __expf(-scan);
    const float wi0 = E0 - e0;
    const float wi1 = e0 - e1;
    const float wi2 = e1 - e2;
    const float wi3 = e2 - e3;

    fvec4 wiv; wiv.x = wi0; wiv.y = wi1; wiv.z = wi2; wiv.w = wi3;
    __builtin_nontemporal_store(wiv, (fvec4*)(out_wi + sbase));

    float r = wi0 * c0.x + wi1 * c0.w + wi2 * c1.z + wi3 * c2.y;
    float g = wi0 * c0.y + wi1 * c1.x + wi2 * c1.w + wi3 * c2.z;
    float b = wi0 * c0.z + wi1 * c1.y + wi2 * c2.x + wi3 * c2.w;
    float d = wi0 * tv.x + wi1 * tv.y + wi2 * tv.z + wi3 * tv.w;

    #pragma unroll
    for (int off = 16; off >= 1; off >>= 1) {
        r += __shfl_xor(r, off, 32);
        g += __shfl_xor(g, off, 32);
        b += __shfl_xor(b, off, 32);
        d += __shfl_xor(d, off, 32);
    }

    if (seglane == 0) {
        out_color[(long)ray * 3 + 0] = r;
        out_color[(long)ray * 3 + 1] = g;
        out_color[(long)ray * 3 + 2] = b;
        out_depth[ray] = d;
    }
}

// ---------------- K2: pure copy t -> out_t ----------------
#define COPY_BLOCKS 2048
#define COPY_VEC4   (NRAYS * S / 4)   // 2,097,152 float4s

__global__ __launch_bounds__(256) void nerf_tcopy_kernel(
    const float* __restrict__ t,
    float* __restrict__ out_t)
{
    const fvec4* src = (const fvec4*)t;
    fvec4* dst = (fvec4*)out_t;
    const int stride = COPY_BLOCKS * 256;        // 524,288 threads
    int idx = blockIdx.x * 256 + threadIdx.x;
    #pragma unroll
    for (int i = 0; i < COPY_VEC4 / (COPY_BLOCKS * 256); ++i) {   // 4 iters
        __builtin_nontemporal_store(src[idx], dst + idx);
        idx += stride;
    }
}

extern "C" void kernel_launch(void* const* d_in, const int* in_sizes, int n_in,
                              void* d_out, int out_size, void* d_ws, size_t ws_size,
                              hipStream_t stream) {
    const float* t     = (const float*)d_in[0];
    const float* sigma = (const float*)d_in[1];
    const float* color = (const float*)d_in[2];

    float* out = (float*)d_out;
    float* out_color = out;                         // N*3
    float* out_depth = out_color + (long)NRAYS * 3; // N
    float* out_wi    = out_depth + NRAYS;           // N*S
    float* out_t     = out_wi + (long)NRAYS * S;    // N*S

    // K2 first: copy t while its pages are L3-warm from the harness restore.
    nerf_tcopy_kernel<<<COPY_BLOCKS, 256, 0, stream>>>(t, out_t);

    const int blocks = NRAYS / RAYS_PER_BLOCK;      // 8192
    nerf_integrate_kernel<<<blocks, 256, 0, stream>>>(
        t, sigma, color, out_color, out_depth, out_wi);
}

// Round 5
// 211.130 us; speedup vs baseline: 1.0273x; 1.0180x over previous
//
#include <hip/hip_runtime.h>
#include <math.h>

// NeRF ray integration, v5 = v4 split + NONTEMPORAL LOADS on all input
// streams (nt flag: LRU/allocate bypass). Probes whether the Infinity-Cache
// hit-serving read path is what pins the integrate kernel at ~3.4 TB/s
// effective while fill dispatches in the same window sustain 6.8 TB/s.
// K2: pure float4 copy t -> out_t. K1: integrate (2 rays/wave, 4
// samples/lane, float4), no t store.

#define NRAYS 65536
#define S 128
#define RAYS_PER_BLOCK 8   // K1: 4 waves * 2 rays

typedef float __attribute__((ext_vector_type(4))) fvec4;

// ---------------- K1: integrate (no t copy) ----------------
__global__ __launch_bounds__(256) void nerf_integrate_kernel(
    const float* __restrict__ t,
    const float* __restrict__ sigma,
    const float* __restrict__ color,
    float* __restrict__ out_color,   // [N,3]
    float* __restrict__ out_depth,   // [N,1]
    float* __restrict__ out_wi)      // [N,S]
{
    const int lane    = threadIdx.x & 63;
    const int seglane = lane & 31;
    const int wave    = threadIdx.x >> 6;
    const int ray = blockIdx.x * RAYS_PER_BLOCK + wave * 2 + (lane >> 5);

    const long sbase = (long)ray * S + 4 * seglane;

    const fvec4 tv = __builtin_nontemporal_load((const fvec4*)(t + sbase));
    const fvec4 sv = __builtin_nontemporal_load((const fvec4*)(sigma + sbase));
    const fvec4* cp = (const fvec4*)(color + (long)ray * (S * 3) + 12 * seglane);
    const fvec4 c0 = __builtin_nontemporal_load(cp + 0);
    const fvec4 c1 = __builtin_nontemporal_load(cp + 1);
    const fvec4 c2 = __builtin_nontemporal_load(cp + 2);

    const float t_next = __shfl_down(tv.x, 1, 32);
    const float dt0 = tv.y - tv.x;
    const float dt1 = tv.z - tv.y;
    const float dt2 = tv.w - tv.z;
    const float dt3 = (seglane == 31) ? 0.0f : (t_next - tv.w);

    const float p0  = sv.x * dt0;
    const float p1  = p0 + sv.y * dt1;
    const float p2  = p1 + sv.z * dt2;
    const float tot = p2 + sv.w * dt3;

    float scan = tot;
    #pragma unroll
    for (int off = 1; off < 32; off <<= 1) {
        const float v = __shfl_up(scan, off, 32);
        if (seglane >= off) scan += v;
    }
    const float excl = scan - tot;

    const float E0 = __expf(-excl);
    const float e0 = __expf(-(excl + p0));
    const float e1 = __expf(-(excl + p1));
    const float e2 = __expf(-(excl + p2));
    const float e3 = __expf(-scan);
    const float wi0 = E0 - e0;
    const float wi1 = e0 - e1;
    const float wi2 = e1 - e2;
    const float wi3 = e2 - e3;

    fvec4 wiv; wiv.x = wi0; wiv.y = wi1; wiv.z = wi2; wiv.w = wi3;
    __builtin_nontemporal_store(wiv, (fvec4*)(out_wi + sbase));

    float r = wi0 * c0.x + wi1 * c0.w + wi2 * c1.z + wi3 * c2.y;
    float g = wi0 * c0.y + wi1 * c1.x + wi2 * c1.w + wi3 * c2.z;
    float b = wi0 * c0.z + wi1 * c1.y + wi2 * c2.x + wi3 * c2.w;
    float d = wi0 * tv.x + wi1 * tv.y + wi2 * tv.z + wi3 * tv.w;

    #pragma unroll
    for (int off = 16; off >= 1; off >>= 1) {
        r += __shfl_xor(r, off, 32);
        g += __shfl_xor(g, off, 32);
        b += __shfl_xor(b, off, 32);
        d += __shfl_xor(d, off, 32);
    }

    if (seglane == 0) {
        out_color[(long)ray * 3 + 0] = r;
        out_color[(long)ray * 3 + 1] = g;
        out_color[(long)ray * 3 + 2] = b;
        out_depth[ray] = d;
    }
}

// ---------------- K2: pure copy t -> out_t ----------------
#define COPY_BLOCKS 2048
#define COPY_VEC4   (NRAYS * S / 4)   // 2,097,152 float4s

__global__ __launch_bounds__(256) void nerf_tcopy_kernel(
    const float* __restrict__ t,
    float* __restrict__ out_t)
{
    const fvec4* src = (const fvec4*)t;
    fvec4* dst = (fvec4*)out_t;
    const int stride = COPY_BLOCKS * 256;        // 524,288 threads
    int idx = blockIdx.x * 256 + threadIdx.x;
    #pragma unroll
    for (int i = 0; i < COPY_VEC4 / (COPY_BLOCKS * 256); ++i) {   // 4 iters
        const fvec4 v = __builtin_nontemporal_load(src + idx);
        __builtin_nontemporal_store(v, dst + idx);
        idx += stride;
    }
}

extern "C" void kernel_launch(void* const* d_in, const int* in_sizes, int n_in,
                              void* d_out, int out_size, void* d_ws, size_t ws_size,
                              hipStream_t stream) {
    const float* t     = (const float*)d_in[0];
    const float* sigma = (const float*)d_in[1];
    const float* color = (const float*)d_in[2];

    float* out = (float*)d_out;
    float* out_color = out;                         // N*3
    float* out_depth = out_color + (long)NRAYS * 3; // N
    float* out_wi    = out_depth + NRAYS;           // N*S
    float* out_t     = out_wi + (long)NRAYS * S;    // N*S

    // K2 first: copy t while its pages are warm from the harness restore.
    nerf_tcopy_kernel<<<COPY_BLOCKS, 256, 0, stream>>>(t, out_t);

    const int blocks = NRAYS / RAYS_PER_BLOCK;      // 8192
    nerf_integrate_kernel<<<blocks, 256, 0, stream>>>(
        t, sigma, color, out_color, out_depth, out_wi);
}